// Round 9
// baseline (15590.709 us; speedup 1.0000x reference)
//
#include <hip/hip_runtime.h>

#define BB 32
#define TT 2048
#define HH 256
#define QB 8    // batches per community
#define NT 512

typedef unsigned long long ull;
typedef unsigned int uint;

__device__ __forceinline__ float sigm(float v) { return 1.0f / (1.0f + __expf(-v)); }

__device__ __forceinline__ int aload(const int* p) {
  return __hip_atomic_load(p, __ATOMIC_RELAXED, __HIP_MEMORY_SCOPE_AGENT);
}
__device__ __forceinline__ void astore(int* p, int v) {
  __hip_atomic_store(p, v, __ATOMIC_RELAXED, __HIP_MEMORY_SCOPE_AGENT);
}
__device__ __forceinline__ ull aload64(const ull* p) {
  return __hip_atomic_load(p, __ATOMIC_RELAXED, __HIP_MEMORY_SCOPE_AGENT);
}
__device__ __forceinline__ void astore64(ull* p, ull v) {
  __hip_atomic_store(p, v, __ATOMIC_RELAXED, __HIP_MEMORY_SCOPE_AGENT);
}

// Communities: c = layer*4 + grp (8 total, XCD-aligned via c = bid&7), 16 WGs each.
// ws: markers m[8][16] ints at +0; rings at +4096:
//   community ring = 4 slots (depth-4) x 2048 pairs {tag(lo32), hbits(hi32)},
//   pair idx = bl*256 + col. 64 KB/community, 512 KB total.
__global__ __launch_bounds__(NT) void lstm_scan(
    const float* __restrict__ x,     // [B,T,H]
    const float* __restrict__ W,     // [L,4,H,2H]
    const float* __restrict__ bias,  // [L,4,H]
    float* __restrict__ out,         // [B,T,H] + hT[B,H] + cT[B,H]
    ull* __restrict__ ring,
    int* __restrict__ sync)
{
    const int bid   = blockIdx.x;
    const int c     = bid & 7;        // community == XCD slot
    const int ug    = bid >> 3;       // unit group 0..15
    const int layer = c >> 2;
    const int grp   = c & 3;          // batch group
    const int tid   = threadIdx.x;
    const int bl    = tid & 7;        // local batch
    const int gate  = (tid >> 3) & 3; // 0=i 1=f 2=o 3=chat
    const int unit  = tid >> 5;       // 0..15
    const int col   = ug * 16 + unit;
    const int bglob = grp * 8 + bl;

    int* mOwn = sync + c * 16;
    int* mSib = sync + (4 + grp) * 16;             // layer-1 community, same grp
    ull* ringOwn = ring + (size_t)c * 8192;        // 4 slots x 2048
    ull* ringIn  = ring + (size_t)grp * 8192;      // layer-0 community, same grp

    __shared__ float wlds[64][516];  // row r = unit*4+gate
    __shared__ float inp[QB][260];
    __shared__ float hrec[QB][260];

    for (int rr = 0; rr < 64; ++rr) {
        const float* wrow =
            W + (((size_t)layer * 4 + (rr & 3)) * HH + (ug * 16 + (rr >> 2))) * (2 * HH);
        wlds[rr][tid] = wrow[tid];
    }
    __syncthreads();

    const int r = unit * 4 + gate;
    const float bg = bias[((size_t)layer * 4 + gate) * HH + col];
    const float4* wx4 = (const float4*)&wlds[r][0];
    const float4* wh4 = (const float4*)&wlds[r][256];

    const int prow = tid >> 6;          // staging row (local batch)
    const int pcol = (tid & 63) << 2;   // staging col base (4 pairs/thread)

    float c_state = 0.f;

    for (int t = 0; t < TT; ++t) {
        const ull* rrec = ringOwn + ((t + 3) & 3) * 2048 + 4 * tid;  // h_l(t-1), tag t
        const uint wantR = (uint)t;

        // ---- (1) pre-issue recurrent poll loads (overlap with stage + x-dot) ----
        ull pre0 = aload64(&rrec[0]);
        ull pre1 = aload64(&rrec[1]);
        ull pre2 = aload64(&rrec[2]);
        ull pre3 = aload64(&rrec[3]);

        // ---- (2) input stage: x (layer0) or h0 ring poll (layer1) ----
        if (layer == 0) {
            *(float4*)&inp[prow][pcol] =
                *(const float4*)(x + ((size_t)(grp * 8 + prow) * TT + t) * HH + pcol);
        } else {
            const ull* rin = ringIn + (t & 3) * 2048 + 4 * tid;  // h0(t), tag t+1
            const uint want = (uint)(t + 1);
            uint pend = 0xFu; ull v[4]; int tries = 0;
            for (;;) {
                #pragma unroll
                for (int j = 0; j < 4; ++j)
                    if (pend & (1u << j)) v[j] = aload64(&rin[j]);
                #pragma unroll
                for (int j = 0; j < 4; ++j)
                    if ((pend & (1u << j)) && (uint)v[j] == want) {
                        inp[prow][pcol + j] = __uint_as_float((uint)(v[j] >> 32));
                        pend &= ~(1u << j);
                    }
                if (!pend) break;
                if (++tries > 8) __builtin_amdgcn_s_sleep(2);
            }
        }
        __syncthreads();  // inp ready

        // ---- (3) x-part dot (K=256) — poll loads in flight under this ----
        const float4* xr = (const float4*)&inp[bl][0];
        float acc = bg, acc2 = 0.f;
        #pragma unroll 8
        for (int c4 = 0; c4 < 32; ++c4) {
            float4 a = xr[2 * c4], a2 = xr[2 * c4 + 1];
            float4 w = wx4[2 * c4], w2 = wx4[2 * c4 + 1];
            acc  += a.x * w.x + a.y * w.y + a.z * w.z + a.w * w.w;
            acc2 += a2.x * w2.x + a2.y * w2.y + a2.z * w2.z + a2.w * w2.w;
        }

        // ---- (4) resolve recurrent poll -> hrec ----
        {
            uint pend = 0xFu;
            if ((uint)pre0 == wantR) { hrec[prow][pcol + 0] = __uint_as_float((uint)(pre0 >> 32)); pend &= ~1u; }
            if ((uint)pre1 == wantR) { hrec[prow][pcol + 1] = __uint_as_float((uint)(pre1 >> 32)); pend &= ~2u; }
            if ((uint)pre2 == wantR) { hrec[prow][pcol + 2] = __uint_as_float((uint)(pre2 >> 32)); pend &= ~4u; }
            if ((uint)pre3 == wantR) { hrec[prow][pcol + 3] = __uint_as_float((uint)(pre3 >> 32)); pend &= ~8u; }
            ull v[4]; int tries = 0;
            while (pend) {
                #pragma unroll
                for (int j = 0; j < 4; ++j)
                    if (pend & (1u << j)) v[j] = aload64(&rrec[j]);
                #pragma unroll
                for (int j = 0; j < 4; ++j)
                    if ((pend & (1u << j)) && (uint)v[j] == wantR) {
                        hrec[prow][pcol + j] = __uint_as_float((uint)(v[j] >> 32));
                        pend &= ~(1u << j);
                    }
                if (++tries > 8) __builtin_amdgcn_s_sleep(2);
            }
        }

        // ---- (5) depth-4 WAR gate (first-try pass in steady state) ----
        // writing h(t) into slot t&3 kills h(t-4); own readers staged it at step t-3
        // (marker t-2); sib (L1 input) staged h0(t-4) at step t-4 (marker t-3).
        if (t >= 3) {
            if (tid < 16)                    { while (aload(&mOwn[tid]) < t - 2)      __builtin_amdgcn_s_sleep(1); }
            else if (layer == 0 && tid < 32) { while (aload(&mSib[tid - 16]) < t - 3) __builtin_amdgcn_s_sleep(1); }
        }
        __syncthreads();  // hrec ready + gate passed
        if (tid == 0) astore(&mOwn[ug], t + 1);  // staged step t (inp + hrec consumed)

        // ---- (6) h-part dot (K=256) + activations + publish ----
        const float4* hr = (const float4*)&hrec[bl][0];
        #pragma unroll 8
        for (int c4 = 0; c4 < 32; ++c4) {
            float4 a = hr[2 * c4], a2 = hr[2 * c4 + 1];
            float4 w = wh4[2 * c4], w2 = wh4[2 * c4 + 1];
            acc  += a.x * w.x + a.y * w.y + a.z * w.z + a.w * w.w;
            acc2 += a2.x * w2.x + a2.y * w2.y + a2.z * w2.z + a2.w * w2.w;
        }
        acc += acc2;
        float f_ = __shfl_xor(acc, 8);
        float o_ = __shfl_xor(acc, 16);
        float q_ = __shfl_xor(acc, 24);
        if (gate == 0) {
            float ig = sigm(acc), fg = sigm(f_), og = sigm(o_), ch = tanhf(q_);
            c_state = fg * c_state + ig * ch;
            float hn = og * tanhf(c_state);
            astore64(&ringOwn[(t & 3) * 2048 + bl * 256 + col],
                     ((ull)__float_as_uint(hn) << 32) | (ull)(uint)(t + 1));
            if (layer == 1) {
                out[((size_t)bglob * TT + t) * HH + col] = hn;
                if (t == TT - 1) {
                    float* tail = out + (size_t)BB * TT * HH;
                    tail[bglob * HH + col] = hn;                // hT (last layer)
                    tail[BB * HH + bglob * HH + col] = c_state; // cT (last layer)
                }
            }
        }
        __syncthreads();  // protect inp/hrec before next iteration overwrites
    }
}

extern "C" void kernel_launch(void* const* d_in, const int* in_sizes, int n_in,
                              void* d_out, int out_size, void* d_ws, size_t ws_size,
                              hipStream_t stream) {
    (void)in_sizes; (void)n_in; (void)out_size; (void)ws_size;
    const float* x    = (const float*)d_in[0];
    const float* W    = (const float*)d_in[1];
    const float* bias = (const float*)d_in[2];
    float* out  = (float*)d_out;
    int*   sync = (int*)d_ws;
    ull*   ring = (ull*)((char*)d_ws + 4096);  // 8 communities x 64 KB = 512 KB

    hipMemsetAsync(d_ws, 0, 4096 + 8 * 8192 * sizeof(ull), stream);  // markers + ring tags
    hipLaunchKernelGGL(lstm_scan, dim3(128), dim3(NT), 0, stream, x, W, bias, out, ring, sync);
}